// Round 5
// baseline (66673.706 us; speedup 1.0000x reference)
//
#include <hip/hip_runtime.h>

#define BB 32
#define SS 64
#define TT 64
#define VV 32000
#define EE 512
#define HH 1024
#define GRID 512
#define BLK 512
#define FLTMAX 3.402823466e38f

typedef unsigned long long u64;

struct Par {
  const int *src, *tgt, *tmask;
  const float *enc_embed, *dec_embed;
  const float *enc_wih0, *enc_whh0, *enc_b0;
  const float *enc_wih1, *enc_whh1, *enc_b1;
  const float *dec_wih0, *dec_whh0, *dec_b0;
  const float *dec_wih1, *dec_whh1, *dec_b1;
  const float *fc_w, *fc_b;
  float *out;
  float *hA0, *hA1, *hB0, *hB1;   // cross-block state (coherent access only)
  float *cA, *cB;                 // [GRID][64] block-private cell state
  float2 *cand;                   // [500][32] per-tile argmax candidates
  int *arr; int *gen;
};

__device__ __forceinline__ float sigf(float x) { return 1.0f / (1.0f + expf(-x)); }

// ---- coherent agent-scope RELAXED access (no L2-invalidate fences) --------
__device__ __forceinline__ float2 ldc2(const float* p) {
  u64 v = __hip_atomic_load((const u64*)p, __ATOMIC_RELAXED, __HIP_MEMORY_SCOPE_AGENT);
  union { u64 u; float2 f; } c; c.u = v; return c.f;
}
__device__ __forceinline__ void stc2(float* p, float x, float y) {
  union { u64 u; float2 f; } c; c.f = make_float2(x, y);
  __hip_atomic_store((u64*)p, c.u, __ATOMIC_RELAXED, __HIP_MEMORY_SCOPE_AGENT);
}
__device__ __forceinline__ void stc1(float* p, float x) {
  __hip_atomic_store(p, x, __ATOMIC_RELAXED, __HIP_MEMORY_SCOPE_AGENT);
}

// ---------------------------------------------------------------------------
// Fence-free grid barrier (512 blocks, all resident at 2 blocks/CU).
// Shared data moves via write-through coherent stores; visibility needs only
// vmcnt(0) before the arrival store. gen is monotonic (no reset race).
// ---------------------------------------------------------------------------
__device__ __forceinline__ void gbar(int* arr, int* gen, int target) {
  __syncthreads();
  asm volatile("s_waitcnt vmcnt(0)" ::: "memory");
  if (blockIdx.x == 0) {
    if (threadIdx.x < 64) {
      int s = threadIdx.x;
      for (;;) {
        bool ok = true;
#pragma unroll
        for (int o = 0; o < GRID; o += 64) {
          int a = (s + o == 0) ? target
              : __hip_atomic_load(arr + s + o, __ATOMIC_RELAXED, __HIP_MEMORY_SCOPE_AGENT);
          ok &= (a >= target);
        }
        if (__all(ok)) break;
        __builtin_amdgcn_s_sleep(1);
      }
    }
    __syncthreads();
    if (threadIdx.x == 0)
      __hip_atomic_store(gen, target, __ATOMIC_RELAXED, __HIP_MEMORY_SCOPE_AGENT);
  } else {
    if (threadIdx.x == 0) {
      __hip_atomic_store(arr + blockIdx.x, target, __ATOMIC_RELAXED, __HIP_MEMORY_SCOPE_AGENT);
      while (__hip_atomic_load(gen, __ATOMIC_RELAXED, __HIP_MEMORY_SCOPE_AGENT) < target)
        __builtin_amdgcn_s_sleep(1);
    }
    __syncthreads();
  }
  asm volatile("" ::: "memory");
}

// ---------------------------------------------------------------------------
// LSTM layer slice: block owns 2 u's (8 gate-rows). Weights staged via LDS:
// wave w stages gate-row w with ONE coalesced float4/lane per 256-k chunk
// (1KB/instr), compute reads them back as LDS broadcast (conflict-free).
// Threads: b = tid&31 (x/h lane-distinct), tc = tid>>5 (16 k-slices of 16).
// ---------------------------------------------------------------------------
__device__ __forceinline__ void lstm_sub(
    const float* __restrict__ xembed, const int* stokLDS,
    const float* __restrict__ xcoh, int lenx,
    const float* __restrict__ hsrc,
    const float* __restrict__ wih, const float* __restrict__ whh,
    const float* __restrict__ bias,
    float* __restrict__ hdst, float* __restrict__ cpriv, float* SH)
{
  const int tid = threadIdx.x;
  const int b = tid & 31, tc = tid >> 5;
  const int lane = tid & 63, wid = tid >> 6;
  const int u0 = blockIdx.x * 2;
  float* wbuf = SH;             // [8][256]
  float* red  = SH + 2048;      // [16][8][33]
  float acc[8] = {0,0,0,0,0,0,0,0};
  const int ncx = lenx >> 8;
  const int gq = wid >> 1, ulq = wid & 1;
  const size_t wxrow = (size_t)(gq * HH + u0 + ulq) * lenx;
  const size_t whrow = (size_t)(gq * HH + u0 + ulq) * HH;

  for (int c = 0; c < ncx + 4; ++c) {
    const bool isx = (c < ncx);
    const int col = (isx ? c : c - ncx) << 8;
    __syncthreads();
    {   // stage this chunk's 8 gate-rows: wave wid -> row q=wid
      const float* srcw = isx ? (wih + wxrow + col) : (whh + whrow + col);
      float4 w = *(reinterpret_cast<const float4*>(srcw) + lane);
      *reinterpret_cast<float4*>(wbuf + (wid << 8) + (lane << 2)) = w;
    }
    float xr[16];
    if (isx) {
      if (xembed) {
        int tk = stokLDS[b];
        if (tk) {
          const float4* s4 = reinterpret_cast<const float4*>(
              xembed + (size_t)tk * lenx + col + (tc << 4));
#pragma unroll
          for (int e = 0; e < 4; ++e) {
            float4 v = s4[e];
            xr[e*4]=v.x; xr[e*4+1]=v.y; xr[e*4+2]=v.z; xr[e*4+3]=v.w;
          }
        } else {
#pragma unroll
          for (int e = 0; e < 16; ++e) xr[e] = 0.f;
        }
      } else {
        const float* xp = xcoh + (size_t)b * lenx + col + (tc << 4);
#pragma unroll
        for (int e = 0; e < 8; ++e) { float2 v = ldc2(xp + 2*e); xr[2*e]=v.x; xr[2*e+1]=v.y; }
      }
    } else {
      const float* xp = hsrc + (size_t)b * HH + col + (tc << 4);
#pragma unroll
      for (int e = 0; e < 8; ++e) { float2 v = ldc2(xp + 2*e); xr[2*e]=v.x; xr[2*e+1]=v.y; }
    }
    __syncthreads();
#pragma unroll
    for (int q = 0; q < 8; ++q) {
      const float4* w4 = reinterpret_cast<const float4*>(wbuf + (q << 8) + (tc << 4));
      float4 w0 = w4[0], w1 = w4[1], w2 = w4[2], w3 = w4[3];
      acc[q] += xr[0]*w0.x + xr[1]*w0.y + xr[2]*w0.z + xr[3]*w0.w
              + xr[4]*w1.x + xr[5]*w1.y + xr[6]*w1.z + xr[7]*w1.w
              + xr[8]*w2.x + xr[9]*w2.y + xr[10]*w2.z + xr[11]*w2.w
              + xr[12]*w3.x + xr[13]*w3.y + xr[14]*w3.z + xr[15]*w3.w;
    }
  }
#pragma unroll
  for (int q = 0; q < 8; ++q) red[(tc * 8 + q) * 33 + b] = acc[q];
  __syncthreads();
  if (tid < 64) {
    int bb = tid & 31, uls = tid >> 5;
    float gv[4];
#pragma unroll
    for (int g2 = 0; g2 < 4; ++g2) {
      float s = bias[g2 * HH + u0 + uls];
#pragma unroll
      for (int t2 = 0; t2 < 16; ++t2) s += red[(t2 * 8 + g2 * 2 + uls) * 33 + bb];
      gv[g2] = s;
    }
    int ci = (bb << 1) + uls;
    float cn = sigf(gv[1]) * cpriv[ci] + sigf(gv[0]) * tanhf(gv[2]);
    float hn = sigf(gv[3]) * tanhf(cn);
    cpriv[ci] = cn;
    stc1(hdst + (size_t)bb * HH + u0 + uls, hn);
  }
  __syncthreads();
}

// ---------------------------------------------------------------------------
__global__ __launch_bounds__(BLK, 4) void mega(Par p) {
  __shared__ float SH[8448];        // 33.8KB union: lstm wbuf+red / FC x+reduce
  __shared__ int   stok[32];
  __shared__ float sav[16][32];
  __shared__ int   sai[16][32];

  const int tid = threadIdx.x;
  const int bid = blockIdx.x;
  const int gid = bid * BLK + tid;
  int gen = 0;

  float* cApriv = p.cA + bid * 64;
  float* cBpriv = p.cB + bid * 64;

  // ---- init: zero h buffers, private c, out[:,0,:]
  for (int i = gid * 2; i < 4 * BB * HH; i += GRID * BLK * 2)
    stc2(p.hA0 + i, 0.f, 0.f);                 // hA0,hA1,hB0,hB1 contiguous
  if (tid < 64) { cApriv[tid] = 0.f; cBpriv[tid] = 0.f; }
  for (long g2 = gid; g2 < (long)BB * VV; g2 += (long)GRID * BLK) {
    int b = (int)(g2 / VV), v = (int)(g2 - (long)b * VV);
    __builtin_nontemporal_store(0.f, p.out + (size_t)b * TT * VV + v);
  }
  gbar(p.arr, p.gen, ++gen);

  // ---- encoder: merged L0(tt) || L1(tt-1)
  for (int tt = 0; tt <= SS; ++tt) {
    if (tt < SS && tid < 32) stok[tid] = p.src[tid * SS + tt];
    __syncthreads();
    float* hAev = (tt & 1) ? p.hA1 : p.hA0;
    float* hAod = (tt & 1) ? p.hA0 : p.hA1;
    float* hBev = (tt & 1) ? p.hB1 : p.hB0;
    float* hBod = (tt & 1) ? p.hB0 : p.hB1;
    if (tt < SS)
      lstm_sub(p.enc_embed, stok, nullptr, EE, hAod,
               p.enc_wih0, p.enc_whh0, p.enc_b0, hAev, cApriv, SH);
    if (tt >= 1)
      lstm_sub(nullptr, nullptr, hAod, HH, hBev,
               p.enc_wih1, p.enc_whh1, p.enc_b1, hBod, cBpriv, SH);
    gbar(p.arr, p.gen, ++gen);
  }

  // ---- decoder
  for (int k = 0; k < TT - 1; ++k) {
    int t = k + 1;
    // build step-k input tokens (redundantly per block)
    if (k == 0) {
      if (tid < 32) stok[tid] = p.tgt[tid * TT];
    } else {
      int b2 = tid & 31, grp = tid >> 5;
      float bv = -FLTMAX; int bi = 0x7fffffff;
      for (int s = grp; s < 500; s += 16) {
        float2 cv = ldc2((const float*)&p.cand[s * 32 + b2]);
        int ci = __float_as_int(cv.y);
        if (cv.x > bv || (cv.x == bv && ci < bi)) { bv = cv.x; bi = ci; }
      }
      sav[grp][b2] = bv; sai[grp][b2] = bi;
      __syncthreads();
      if (tid < 32) {
        float v = sav[0][tid]; int vi = sai[0][tid];
#pragma unroll
        for (int s = 1; s < 16; ++s) {
          float w = sav[s][tid]; int wi = sai[s][tid];
          if (w > v || (w == v && wi < vi)) { v = w; vi = wi; }
        }
        stok[tid] = (p.tmask[k] > 0) ? p.tgt[tid * TT + k] : vi;
      }
    }
    __syncthreads();

    float* hAw = (k & 1) ? p.hA1 : p.hA0;
    float* hAr = (k & 1) ? p.hA0 : p.hA1;
    float* hBw = (k & 1) ? p.hB1 : p.hB0;
    float* hBr = (k & 1) ? p.hB0 : p.hB1;

    lstm_sub(p.dec_embed, stok, nullptr, EE, hAr,
             p.dec_wih0, p.dec_whh0, p.dec_b0, hAw, cApriv, SH);
    gbar(p.arr, p.gen, ++gen);
    lstm_sub(nullptr, nullptr, hAw, HH, hBr,
             p.dec_wih1, p.dec_whh1, p.dec_b1, hBw, cBpriv, SH);
    gbar(p.arr, p.gen, ++gen);

    // ---- FC: 500 blocks x 64 j. lane = j (line-efficient fc_w loads),
    // acc[32 b]/thread, 8-wave K-split, LDS tree reduce, argmax per tile.
    if (bid < 500) {
      const int lane = tid & 63, wid = tid >> 6;
      const int jbase = bid * 64;
      const float* wrow = p.fc_w + (size_t)(jbase + lane) * HH;
      float accF[32];
#pragma unroll
      for (int q = 0; q < 32; ++q) accF[q] = 0.f;
      for (int r = 0; r < 4; ++r) {
        __syncthreads();
        {   // stage h chunk [32][256] (pad 260)
          int sb = tid >> 4, c0 = (tid & 15) << 4;
          const float* xp = hBw + (size_t)sb * HH + (r << 8) + c0;
          float* dd = SH + sb * 260 + c0;
#pragma unroll
          for (int e = 0; e < 4; ++e) {
            float2 v0 = ldc2(xp + 4*e*1 + 0);
            float2 v1 = ldc2(xp + 4*e + 2);
            float4 w; w.x=v0.x; w.y=v0.y; w.z=v1.x; w.w=v1.y;
            *reinterpret_cast<float4*>(dd + 4*e) = w;
          }
        }
        __syncthreads();
        const int ks = wid << 5;       // this wave's 32-k slice in the chunk
#pragma unroll
        for (int g2 = 0; g2 < 8; ++g2) {
          float4 w4 = *reinterpret_cast<const float4*>(wrow + (r << 8) + ks + (g2 << 2));
#pragma unroll
          for (int b2 = 0; b2 < 32; ++b2) {
            const float4 x4 = *reinterpret_cast<const float4*>(SH + b2 * 260 + ks + (g2 << 2));
            accF[b2] += w4.x*x4.x + w4.y*x4.y + w4.z*x4.z + w4.w*x4.w;
          }
        }
      }
      // 8-wave tree reduction in LDS
      __syncthreads();
      if (wid >= 4) {
        int w2 = wid - 4;
#pragma unroll
        for (int b2 = 0; b2 < 32; ++b2) SH[((w2*33 + b2) << 6) + lane] = accF[b2];
      }
      __syncthreads();
      if (wid < 4) {
#pragma unroll
        for (int b2 = 0; b2 < 32; ++b2) accF[b2] += SH[((wid*33 + b2) << 6) + lane];
      }
      __syncthreads();
      if (wid == 2 || wid == 3) {
        int w2 = wid - 2;
#pragma unroll
        for (int b2 = 0; b2 < 32; ++b2) SH[((w2*33 + b2) << 6) + lane] = accF[b2];
      }
      __syncthreads();
      if (wid < 2) {
#pragma unroll
        for (int b2 = 0; b2 < 32; ++b2) accF[b2] += SH[((wid*33 + b2) << 6) + lane];
      }
      __syncthreads();
      if (wid == 1) {
#pragma unroll
        for (int b2 = 0; b2 < 32; ++b2) SH[(b2 << 6) + lane] = accF[b2];
      }
      __syncthreads();
      if (wid == 0) {
        float wb = p.fc_b[jbase + lane];
#pragma unroll
        for (int b2 = 0; b2 < 32; ++b2) {
          float v = accF[b2] + SH[(b2 << 6) + lane] + wb;
          __builtin_nontemporal_store(v,
              p.out + (size_t)b2 * TT * VV + (size_t)t * VV + jbase + lane);
          accF[b2] = v;
        }
      }
      __syncthreads();
      if (wid == 0) {
#pragma unroll
        for (int b2 = 0; b2 < 32; ++b2) SH[b2 * 65 + lane] = accF[b2];
      }
      __syncthreads();
      if (tid < 32) {                  // per-b argmax over this tile's 64 j
        float bv = -FLTMAX; int bi = 0;
        for (int jj = 0; jj < 64; ++jj) {
          float v = SH[tid * 65 + jj];
          if (v > bv) { bv = v; bi = jbase + jj; }
        }
        stc2((float*)&p.cand[bid * 32 + tid], bv, __int_as_float(bi));
      }
    }
    gbar(p.arr, p.gen, ++gen);
  }
}

// ---------------------------------------------------------------------------
extern "C" void kernel_launch(void* const* d_in, const int* in_sizes, int n_in,
                              void* d_out, int out_size, void* d_ws, size_t ws_size,
                              hipStream_t stream) {
  Par p;
  p.src       = (const int*)d_in[0];
  p.tgt       = (const int*)d_in[1];
  p.tmask     = (const int*)d_in[2];
  p.enc_embed = (const float*)d_in[3];
  p.dec_embed = (const float*)d_in[4];
  p.enc_wih0  = (const float*)d_in[5];
  p.enc_whh0  = (const float*)d_in[6];
  p.enc_b0    = (const float*)d_in[7];
  p.enc_wih1  = (const float*)d_in[8];
  p.enc_whh1  = (const float*)d_in[9];
  p.enc_b1    = (const float*)d_in[10];
  p.dec_wih0  = (const float*)d_in[11];
  p.dec_whh0  = (const float*)d_in[12];
  p.dec_b0    = (const float*)d_in[13];
  p.dec_wih1  = (const float*)d_in[14];
  p.dec_whh1  = (const float*)d_in[15];
  p.dec_b1    = (const float*)d_in[16];
  p.fc_w      = (const float*)d_in[17];
  p.fc_b      = (const float*)d_in[18];
  p.out       = (float*)d_out;

  p.arr = (int*)d_ws;                       // 512 ints
  p.gen = (int*)((char*)d_ws + 2560);       // own line, inside memset
  float* f = (float*)((char*)d_ws + 4096);
  p.hA0 = f; f += BB * HH;                  // keep hA0..hB1 contiguous
  p.hA1 = f; f += BB * HH;
  p.hB0 = f; f += BB * HH;
  p.hB1 = f; f += BB * HH;
  p.cA  = f; f += GRID * 64;
  p.cB  = f; f += GRID * 64;
  p.cand = (float2*)f;                      // 500*32 float2

  hipMemsetAsync(d_ws, 0, 4096, stream);
  mega<<<dim3(GRID), dim3(BLK), 0, stream>>>(p);
}

// Round 6
// 17213.957 us; speedup vs baseline: 3.8732x; 3.8732x over previous
//
#include <hip/hip_runtime.h>

#define BB 32
#define SS 64
#define TT 64
#define VV 32000
#define EE 512
#define HH 1024
#define GRID 512
#define BLK 512
#define FLTMAX 3.402823466e38f

typedef unsigned long long u64;

struct Par {
  const int *src, *tgt, *tmask;
  const float *enc_embed, *dec_embed;
  const float *enc_wih0, *enc_whh0, *enc_b0;
  const float *enc_wih1, *enc_whh1, *enc_b1;
  const float *dec_wih0, *dec_whh0, *dec_b0;
  const float *dec_wih1, *dec_whh1, *dec_b1;
  const float *fc_w, *fc_b;
  float *out;
  float *hA0, *hA1, *hB0, *hB1;   // cross-block state (coherent access only)
  float *cA, *cB;                 // block-private cell state [256][128] each
  float2 *cand;                   // [500][32]
  int *tok;                       // [32]
  int *arr; int *gen;
};

__device__ __forceinline__ float sigf(float x) { return 1.0f / (1.0f + expf(-x)); }

// ---- coherent agent-scope RELAXED access (no L2-invalidate fences) --------
__device__ __forceinline__ float2 ldc2(const float* p) {
  u64 v = __hip_atomic_load((const u64*)p, __ATOMIC_RELAXED, __HIP_MEMORY_SCOPE_AGENT);
  union { u64 u; float2 f; } c; c.u = v; return c.f;
}
__device__ __forceinline__ void stc2(float* p, float x, float y) {
  union { u64 u; float2 f; } c; c.f = make_float2(x, y);
  __hip_atomic_store((u64*)p, c.u, __ATOMIC_RELAXED, __HIP_MEMORY_SCOPE_AGENT);
}
__device__ __forceinline__ void stc1(float* p, float x) {
  __hip_atomic_store(p, x, __ATOMIC_RELAXED, __HIP_MEMORY_SCOPE_AGENT);
}
__device__ __forceinline__ int ldci(const int* p) {
  return __hip_atomic_load(p, __ATOMIC_RELAXED, __HIP_MEMORY_SCOPE_AGENT);
}

// ---------------------------------------------------------------------------
// Fence-free grid barrier. __syncthreads drains each wave's vmcnt (HIP emits
// s_waitcnt vmcnt(0) before s_barrier), so all waves' write-through stores are
// globally visible before wave 0 signals arrival.
// ---------------------------------------------------------------------------
__device__ __forceinline__ void gbar(int* arr, int* gen, int target) {
  __syncthreads();
  asm volatile("s_waitcnt vmcnt(0)" ::: "memory");
  if (blockIdx.x == 0) {
    if (threadIdx.x < 64) {
      int s = threadIdx.x;
      for (;;) {
        bool ok = true;
#pragma unroll
        for (int o = 0; o < GRID; o += 64) {
          int a = (s + o == 0) ? target
              : __hip_atomic_load(arr + s + o, __ATOMIC_RELAXED, __HIP_MEMORY_SCOPE_AGENT);
          ok &= (a >= target);
        }
        if (__all(ok)) break;
        __builtin_amdgcn_s_sleep(1);
      }
    }
    __syncthreads();
    if (threadIdx.x == 0)
      __hip_atomic_store(gen, target, __ATOMIC_RELAXED, __HIP_MEMORY_SCOPE_AGENT);
  } else {
    if (threadIdx.x == 0) {
      __hip_atomic_store(arr + blockIdx.x, target, __ATOMIC_RELAXED, __HIP_MEMORY_SCOPE_AGENT);
      while (__hip_atomic_load(gen, __ATOMIC_RELAXED, __HIP_MEMORY_SCOPE_AGENT) < target)
        __builtin_amdgcn_s_sleep(1);
    }
    __syncthreads();
  }
  asm volatile("" ::: "memory");
}

// ---------------------------------------------------------------------------
// LSTM partial accumulate over one input part. Block owns u0..u0+3 (16 gate
// rows, acc[16]). Weights LDS-staged (1KB/instr coalesced), read back as
// 2-way broadcast b128. Threads: b=tid&31, tc=tid>>5 (16 k-slices of 16).
// ---------------------------------------------------------------------------
__device__ __forceinline__ void lstm_accum(
    const float* __restrict__ tab, const int* __restrict__ stokL,
    const float* __restrict__ xcoh, int lenx,
    const float* __restrict__ W, int u0,
    float* __restrict__ acc, float* __restrict__ wbuf)
{
  const int tid = threadIdx.x;
  const int b = tid & 31, tc = tid >> 5;
  const int lane = tid & 63, wid = tid >> 6;
  const int r2 = wid + 8;
  const float* wr1 = W + (size_t)((wid >> 2) * HH + u0 + (wid & 3)) * lenx + (lane << 2);
  const float* wr2 = W + (size_t)((r2  >> 2) * HH + u0 + (r2  & 3)) * lenx + (lane << 2);
  const int ncx = lenx >> 8;
  for (int c = 0; c < ncx; ++c) {
    const int col = c << 8;
    __syncthreads();
    {
      float4 wA = *reinterpret_cast<const float4*>(wr1 + col);
      float4 wB = *reinterpret_cast<const float4*>(wr2 + col);
      *reinterpret_cast<float4*>(wbuf + (wid << 8) + (lane << 2)) = wA;
      *reinterpret_cast<float4*>(wbuf + (r2  << 8) + (lane << 2)) = wB;
    }
    float xr[16];
    if (tab) {
      const int tk = stokL[b];
      if (tk) {
        const float4* s4 = reinterpret_cast<const float4*>(
            tab + (size_t)tk * lenx + col + (tc << 4));
#pragma unroll
        for (int e = 0; e < 4; ++e) {
          float4 v = s4[e];
          xr[e*4] = v.x; xr[e*4+1] = v.y; xr[e*4+2] = v.z; xr[e*4+3] = v.w;
        }
      } else {
#pragma unroll
        for (int e = 0; e < 16; ++e) xr[e] = 0.f;
      }
    } else {
      const float* xp = xcoh + (size_t)b * lenx + col + (tc << 4);
#pragma unroll
      for (int e = 0; e < 8; ++e) {
        float2 v = ldc2(xp + 2*e); xr[2*e] = v.x; xr[2*e+1] = v.y;
      }
    }
    __syncthreads();
#pragma unroll
    for (int q = 0; q < 16; ++q) {
      const float4* w4 = reinterpret_cast<const float4*>(wbuf + (q << 8) + (tc << 4));
      float4 w0 = w4[0], w1 = w4[1], w2 = w4[2], w3 = w4[3];
      acc[q] += xr[0]*w0.x + xr[1]*w0.y + xr[2]*w0.z + xr[3]*w0.w
              + xr[4]*w1.x + xr[5]*w1.y + xr[6]*w1.z + xr[7]*w1.w
              + xr[8]*w2.x + xr[9]*w2.y + xr[10]*w2.z + xr[11]*w2.w
              + xr[12]*w3.x + xr[13]*w3.y + xr[14]*w3.z + xr[15]*w3.w;
    }
  }
}

// cross-slice reduce + cell + coherent h-store
__device__ __forceinline__ void lstm_finish(
    const float* __restrict__ bias, int u0,
    const float* __restrict__ acc, float* __restrict__ cpriv,
    float* __restrict__ hdst, float* __restrict__ SH)
{
  const int tid = threadIdx.x;
  const int b = tid & 31, tc = tid >> 5;
  float* red = SH + 4096;
  __syncthreads();
#pragma unroll
  for (int q = 0; q < 16; ++q) red[(tc * 16 + q) * 33 + b] = acc[q];
  __syncthreads();
  if (tid < 128) {
    int bb = tid & 31, ul = tid >> 5;
    float g[4];
#pragma unroll
    for (int gg = 0; gg < 4; ++gg) {
      float s = bias[gg * HH + u0 + ul];
#pragma unroll
      for (int t2 = 0; t2 < 16; ++t2) s += red[(t2 * 16 + gg * 4 + ul) * 33 + bb];
      g[gg] = s;
    }
    float cn = sigf(g[1]) * cpriv[(bb << 2) + ul] + sigf(g[0]) * tanhf(g[2]);
    float hn = sigf(g[3]) * tanhf(cn);
    cpriv[(bb << 2) + ul] = cn;
    stc1(hdst + (size_t)bb * HH + u0 + ul, hn);
  }
}

// ---------------------------------------------------------------------------
// FC tile: block covers 64 j. thread: jl=lane&31 -> j pair; bg -> 4 b's;
// kh=tid>>8 -> k-half of each 256-chunk. acc[8] ONLY (no spill).
// ---------------------------------------------------------------------------
__device__ __forceinline__ void fc_tile(const Par& p, const float* __restrict__ hsrc,
                                        int t, float* __restrict__ SH)
{
  const int tid = threadIdx.x;
  const int jl = tid & 31;
  const int bg = (tid >> 5) & 7;
  const int kh = tid >> 8;
  const int jbase = blockIdx.x * 64;
  const float* w0 = p.fc_w + (size_t)(jbase + 2 * jl) * HH;
  const float* w1 = w0 + HH;
  float acc[8] = {0.f,0.f,0.f,0.f,0.f,0.f,0.f,0.f};

  for (int r = 0; r < 4; ++r) {
    __syncthreads();
    {   // stage h chunk [32][256] -> SH[32][264]
      int sb = tid >> 4, c0 = (tid & 15) << 4;
      const float* xp = hsrc + (size_t)sb * HH + (r << 8) + c0;
      float* dd = SH + sb * 264 + c0;
#pragma unroll
      for (int e = 0; e < 8; ++e) {
        float2 v = ldc2(xp + 2 * e); dd[2*e] = v.x; dd[2*e+1] = v.y;
      }
    }
    __syncthreads();
    const int kb = (r << 8) + (kh << 7);
    const float* pw0 = w0 + kb;
    const float* pw1 = w1 + kb;
    const float* px  = SH + (bg << 2) * 264 + (kh << 7);
#pragma unroll 8
    for (int kk = 0; kk < 128; kk += 4) {
      float4 a0 = *reinterpret_cast<const float4*>(pw0 + kk);
      float4 a1 = *reinterpret_cast<const float4*>(pw1 + kk);
#pragma unroll
      for (int bb = 0; bb < 4; ++bb) {
        float4 x4 = *reinterpret_cast<const float4*>(px + bb * 264 + kk);
        acc[bb]     += a0.x*x4.x + a0.y*x4.y + a0.z*x4.z + a0.w*x4.w;
        acc[4 + bb] += a1.x*x4.x + a1.y*x4.y + a1.z*x4.z + a1.w*x4.w;
      }
    }
  }
  // k-half reduce (pad 9 -> conflict-free)
  float* red2 = SH + 8448;
  __syncthreads();
  if (kh == 1) {
    int s = tid - 256;
#pragma unroll
    for (int e = 0; e < 8; ++e) red2[s * 9 + e] = acc[e];
  }
  __syncthreads();
  float* SA = SH + 10752;          // [32][66]
  if (kh == 0) {
#pragma unroll
    for (int e = 0; e < 8; ++e) acc[e] += red2[tid * 9 + e];
    float b0 = p.fc_b[jbase + 2 * jl];
    float b1 = p.fc_b[jbase + 2 * jl + 1];
#pragma unroll
    for (int bb = 0; bb < 4; ++bb) {
      int b = (bg << 2) + bb;
      float v0 = acc[bb] + b0, v1 = acc[4 + bb] + b1;
      union { double d; float2 f; } uu; uu.f = make_float2(v0, v1);
      __builtin_nontemporal_store(uu.d, reinterpret_cast<double*>(
          p.out + (size_t)b * TT * VV + (size_t)t * VV + jbase + 2 * jl));
      SA[b * 66 + 2 * jl] = v0; SA[b * 66 + 2 * jl + 1] = v1;
    }
  }
  __syncthreads();
  if (tid < 32) {                   // per-b argmax over this tile's 64 j
    float bv = -FLTMAX; int bi = 0;
    for (int jj = 0; jj < 64; ++jj) {
      float v = SA[tid * 66 + jj];
      if (v > bv) { bv = v; bi = jbase + jj; }
    }
    stc2((float*)&p.cand[blockIdx.x * 32 + tid], bv, __int_as_float(bi));
  }
}

// AMred: block b (0..31) reduces 500 candidates, teacher-select, store token
__device__ __forceinline__ void amred(const Par& p, int k, float* SH)
{
  const int tid = threadIdx.x;
  const int b = blockIdx.x;
  float bv = -FLTMAX; int bi = 0x7fffffff;
  if (tid < 500) {
    float2 cv = ldc2((const float*)&p.cand[tid * 32 + b]);
    bv = cv.x; bi = __float_as_int(cv.y);
  }
  float* sv = SH; int* si = (int*)(SH + 512);
  sv[tid] = bv; si[tid] = bi;
  __syncthreads();
  for (int s = 256; s > 0; s >>= 1) {
    if (tid < s) {
      float ov = sv[tid + s]; int oi = si[tid + s];
      if (ov > sv[tid] || (ov == sv[tid] && oi < si[tid])) { sv[tid] = ov; si[tid] = oi; }
    }
    __syncthreads();
  }
  if (tid == 0) {
    int tk = (p.tmask[k + 1] > 0) ? p.tgt[b * TT + (k + 1)] : si[0];
    __hip_atomic_store(p.tok + b, tk, __ATOMIC_RELAXED, __HIP_MEMORY_SCOPE_AGENT);
  }
}

// ---------------------------------------------------------------------------
__global__ __launch_bounds__(BLK, 4) void mega(Par p) {
  __shared__ __attribute__((aligned(16))) float SH[12928];
  __shared__ int stok[32];

  const int tid = threadIdx.x;
  const int bid = blockIdx.x;
  const int gid = bid * BLK + tid;
  int gen = 0;

  // ---- init
  for (int i = gid * 2; i < 4 * BB * HH; i += GRID * BLK * 2)
    stc2(p.hA0 + i, 0.f, 0.f);                       // hA0..hB1 contiguous
  if (bid < 256) { if (tid < 128) p.cA[bid * 128 + tid] = 0.f; }
  else           { if (tid < 128) p.cB[(bid - 256) * 128 + tid] = 0.f; }
  for (long g2 = gid; g2 < (long)BB * VV; g2 += (long)GRID * BLK) {
    int b = (int)(g2 / VV), v = (int)(g2 - (long)b * VV);
    __builtin_nontemporal_store(0.f, p.out + (size_t)b * TT * VV + v);
  }
  gbar(p.arr, p.gen, ++gen);

  // ---- encoder: L0(tt) on blocks 0..255  ||  L1(tt-1) on blocks 256..511
  for (int tt = 0; tt <= SS; ++tt) {
    if (tid < 32 && tt < SS) stok[tid] = p.src[tid * SS + tt];
    __syncthreads();
    const int par = tt & 1;
    float* hA_w = par ? p.hA1 : p.hA0;           // L0 writes hA[par]
    float* hA_r = par ? p.hA0 : p.hA1;           // prev hA = L1's x
    float* hB_w = par ? p.hB0 : p.hB1;           // L1 writes hB[1-par]
    float* hB_r = par ? p.hB1 : p.hB0;           // L1 reads hB[par]
    if (bid < 256) {
      if (tt < SS) {
        const int u0 = bid * 4;
        float acc[16] = {0.f};
        lstm_accum(p.enc_embed, stok, nullptr, EE, p.enc_wih0, u0, acc, SH);
        lstm_accum(nullptr, nullptr, hA_r, HH, p.enc_whh0, u0, acc, SH);
        lstm_finish(p.enc_b0, u0, acc, p.cA + bid * 128, hA_w, SH);
      }
    } else {
      if (tt >= 1) {
        const int u0 = (bid - 256) * 4;
        float acc[16] = {0.f};
        lstm_accum(nullptr, nullptr, hA_r, HH, p.enc_wih1, u0, acc, SH);
        lstm_accum(nullptr, nullptr, hB_r, HH, p.enc_whh1, u0, acc, SH);
        lstm_finish(p.enc_b1, u0, acc, p.cB + (bid - 256) * 128, hB_w, SH);
      }
    }
    gbar(p.arr, p.gen, ++gen);
  }

  // ---- decoder: per step: {L0 || L1h} -> {L1x+cell} -> {FC} -> {AMred}
  for (int k = 0; k < TT - 1; ++k) {
    const int par = k & 1;
    float* hA_w = par ? p.hA1 : p.hA0;
    float* hA_r = par ? p.hA0 : p.hA1;           // k=0: hA1 (enc final) ✓
    float* hB_w = par ? p.hB1 : p.hB0;
    float* hB_r = par ? p.hB0 : p.hB1;           // k=0: hB1 (enc final) ✓

    float accB[16];
    // phase a
    if (bid < 256) {
      if (tid < 32) stok[tid] = (k == 0) ? p.tgt[tid * TT] : ldci(p.tok + tid);
      __syncthreads();
      const int u0 = bid * 4;
      float acc[16] = {0.f};
      lstm_accum(p.dec_embed, stok, nullptr, EE, p.dec_wih0, u0, acc, SH);
      lstm_accum(nullptr, nullptr, hA_r, HH, p.dec_whh0, u0, acc, SH);
      lstm_finish(p.dec_b0, u0, acc, p.cA + bid * 128, hA_w, SH);
    } else {
#pragma unroll
      for (int q = 0; q < 16; ++q) accB[q] = 0.f;
      lstm_accum(nullptr, nullptr, hB_r, HH, p.dec_whh1, (bid - 256) * 4, accB, SH);
    }
    gbar(p.arr, p.gen, ++gen);
    // phase b
    if (bid >= 256) {
      const int u0 = (bid - 256) * 4;
      lstm_accum(nullptr, nullptr, hA_w, HH, p.dec_wih1, u0, accB, SH);
      lstm_finish(p.dec_b1, u0, accB, p.cB + (bid - 256) * 128, hB_w, SH);
    }
    gbar(p.arr, p.gen, ++gen);
    // phase c
    if (bid < 500) fc_tile(p, hB_w, k + 1, SH);
    gbar(p.arr, p.gen, ++gen);
    // phase d
    if (k < TT - 2) {
      if (bid < 32) amred(p, k, SH);
      gbar(p.arr, p.gen, ++gen);
    }
  }
}

// ---------------------------------------------------------------------------
extern "C" void kernel_launch(void* const* d_in, const int* in_sizes, int n_in,
                              void* d_out, int out_size, void* d_ws, size_t ws_size,
                              hipStream_t stream) {
  Par p;
  p.src       = (const int*)d_in[0];
  p.tgt       = (const int*)d_in[1];
  p.tmask     = (const int*)d_in[2];
  p.enc_embed = (const float*)d_in[3];
  p.dec_embed = (const float*)d_in[4];
  p.enc_wih0  = (const float*)d_in[5];
  p.enc_whh0  = (const float*)d_in[6];
  p.enc_b0    = (const float*)d_in[7];
  p.enc_wih1  = (const float*)d_in[8];
  p.enc_whh1  = (const float*)d_in[9];
  p.enc_b1    = (const float*)d_in[10];
  p.dec_wih0  = (const float*)d_in[11];
  p.dec_whh0  = (const float*)d_in[12];
  p.dec_b0    = (const float*)d_in[13];
  p.dec_wih1  = (const float*)d_in[14];
  p.dec_whh1  = (const float*)d_in[15];
  p.dec_b1    = (const float*)d_in[16];
  p.fc_w      = (const float*)d_in[17];
  p.fc_b      = (const float*)d_in[18];
  p.out       = (float*)d_out;

  p.arr = (int*)d_ws;                          // 512 ints
  p.gen = (int*)((char*)d_ws + 2176);
  p.tok = (int*)((char*)d_ws + 2304);          // 32 ints
  float* f = (float*)((char*)d_ws + 4096);
  p.hA0 = f; f += BB * HH;
  p.hA1 = f; f += BB * HH;
  p.hB0 = f; f += BB * HH;
  p.hB1 = f; f += BB * HH;
  p.cA  = f; f += 256 * 128;
  p.cB  = f; f += 256 * 128;
  p.cand = (float2*)f; f += 500 * 32 * 2;

  hipMemsetAsync(d_ws, 0, 4096, stream);
  mega<<<dim3(GRID), dim3(BLK), 0, stream>>>(p);
}